// Round 6
// baseline (3320.457 us; speedup 1.0000x reference)
//
#include <hip/hip_runtime.h>
#include <math.h>

#define B_T   128
#define NS    128
#define NQ    512
#define DIN   256
#define DOUT  64

#define MU_SIZE  (B_T*NQ*DOUT)            // 4,194,304 floats
#define SIG_SIZE (B_T*NQ*DOUT*DOUT)       // 268,435,456 floats
#define NLL_IDX  (MU_SIZE + SIG_SIZE)     // 272,629,760

// ---------------------------------------------------------------------------
// K0: Sp = A @ A^T  (fp64 accumulate); also zeroes the NLL accumulator.
// ---------------------------------------------------------------------------
__global__ __launch_bounds__(256) void k_prior_sp(const float* __restrict__ A,
                                                  double* __restrict__ Sp,
                                                  double* __restrict__ NLLACC) {
    __shared__ float Ai[16][260];
    __shared__ float Aj[16][260];
    int bi = blockIdx.x;
    int i0 = (bi >> 4) << 4;
    int j0 = (bi & 15) << 4;
    int tid = threadIdx.x;
    if (bi == 0 && tid == 0) NLLACC[0] = 0.0;
    for (int idx = tid; idx < 16 * 256; idx += 256) {
        int r = idx >> 8, c = idx & 255;
        Ai[r][c] = A[(i0 + r) * 256 + c];
        Aj[r][c] = A[(j0 + r) * 256 + c];
    }
    __syncthreads();
    int r = tid >> 4, c = tid & 15;
    double acc = 0.0;
    for (int k = 0; k < 256; ++k)
        acc += (double)Ai[r][k] * (double)Aj[c][k];
    Sp[(i0 + r) * 256 + (j0 + c)] = acc;
}

// ---------------------------------------------------------------------------
// K1 (merged): by<10 -> G tile; by 10..13 -> RHS tile (no MPN add);
//              by==14 && b<4 -> MPN = Sp @ m_prior (64-row slice per block).
// ---------------------------------------------------------------------------
__global__ __launch_bounds__(256) void k_build(const float* __restrict__ PHI,
                                               const float* __restrict__ Y,
                                               const float* __restrict__ MP,
                                               const double* __restrict__ Sp,
                                               double* __restrict__ G,
                                               double* __restrict__ RHS,
                                               double* __restrict__ MPNo) {
    int b = blockIdx.x, by = blockIdx.y, tid = threadIdx.x;
    if (by == 14) {
        if (b >= 4) return;
        for (int out = tid; out < 4096; out += 256) {
            int r = 64 * b + (out >> 6), cc = out & 63;
            double acc = 0.0;
            for (int t = 0; t < 256; ++t)
                acc += Sp[r * 256 + t] * (double)MP[t * 64 + cc];
            MPNo[r * 64 + cc] = acc;
        }
        return;
    }
    __shared__ float As[128][64];
    __shared__ float Bs[128][64];
    int tx = tid & 15, ty = tid >> 4;
    const float* Pb = PHI + b * (NS * DIN);
    double acc[4][4];
#pragma unroll
    for (int r = 0; r < 4; ++r)
#pragma unroll
        for (int s = 0; s < 4; ++s) acc[r][s] = 0.0;

    if (by < 10) {   // ---- G tile ----
        int ti = 0;
        while (((ti + 1) * (ti + 2)) / 2 <= by) ti++;
        int tj = by - (ti * (ti + 1)) / 2;
        int i0 = ti * 64, j0 = tj * 64;
        for (int idx = tid; idx < 128 * 64; idx += 256) {
            int n = idx >> 6, c = idx & 63;
            As[n][c] = Pb[n * 256 + i0 + c];
            Bs[n][c] = Pb[n * 256 + j0 + c];
        }
        __syncthreads();
        for (int n = 0; n < 128; ++n) {
            float a0 = As[n][4 * ty + 0], a1 = As[n][4 * ty + 1];
            float a2 = As[n][4 * ty + 2], a3 = As[n][4 * ty + 3];
            float b0 = Bs[n][4 * tx + 0], b1 = Bs[n][4 * tx + 1];
            float b2 = Bs[n][4 * tx + 2], b3 = Bs[n][4 * tx + 3];
            acc[0][0] += (double)a0 * b0; acc[0][1] += (double)a0 * b1;
            acc[0][2] += (double)a0 * b2; acc[0][3] += (double)a0 * b3;
            acc[1][0] += (double)a1 * b0; acc[1][1] += (double)a1 * b1;
            acc[1][2] += (double)a1 * b2; acc[1][3] += (double)a1 * b3;
            acc[2][0] += (double)a2 * b0; acc[2][1] += (double)a2 * b1;
            acc[2][2] += (double)a2 * b2; acc[2][3] += (double)a2 * b3;
            acc[3][0] += (double)a3 * b0; acc[3][1] += (double)a3 * b1;
            acc[3][2] += (double)a3 * b2; acc[3][3] += (double)a3 * b3;
        }
        double* Gb = G + b * 65536;
#pragma unroll
        for (int r = 0; r < 4; ++r) {
            int i = i0 + 4 * ty + r;
#pragma unroll
            for (int s = 0; s < 4; ++s) {
                int j = j0 + 4 * tx + s;
                Gb[i * 256 + j] = acc[r][s] + Sp[i * 256 + j];
            }
        }
    } else {        // ---- RHS tile (by 10..13) ----
        int i0 = (by - 10) * 64;
        const float* Yb = Y + b * (NS * DOUT);
        for (int idx = tid; idx < 128 * 64; idx += 256) {
            int n = idx >> 6, c = idx & 63;
            As[n][c] = Pb[n * 256 + i0 + c];
            Bs[n][c] = Yb[n * 64 + c];
        }
        __syncthreads();
        for (int n = 0; n < 128; ++n) {
            float a0 = As[n][4 * ty + 0], a1 = As[n][4 * ty + 1];
            float a2 = As[n][4 * ty + 2], a3 = As[n][4 * ty + 3];
            float y0 = Bs[n][4 * tx + 0], y1 = Bs[n][4 * tx + 1];
            float y2 = Bs[n][4 * tx + 2], y3 = Bs[n][4 * tx + 3];
            acc[0][0] += (double)a0 * y0; acc[0][1] += (double)a0 * y1;
            acc[0][2] += (double)a0 * y2; acc[0][3] += (double)a0 * y3;
            acc[1][0] += (double)a1 * y0; acc[1][1] += (double)a1 * y1;
            acc[1][2] += (double)a1 * y2; acc[1][3] += (double)a1 * y3;
            acc[2][0] += (double)a2 * y0; acc[2][1] += (double)a2 * y1;
            acc[2][2] += (double)a2 * y2; acc[2][3] += (double)a2 * y3;
            acc[3][0] += (double)a3 * y0; acc[3][1] += (double)a3 * y1;
            acc[3][2] += (double)a3 * y2; acc[3][3] += (double)a3 * y3;
        }
        double* Rb = RHS + b * 16384;
#pragma unroll
        for (int r = 0; r < 4; ++r) {
            int i = i0 + 4 * ty + r;
#pragma unroll
            for (int s = 0; s < 4; ++s)
                Rb[i * 64 + 4 * tx + s] = acc[r][s];
        }
    }
}

// ---------------------------------------------------------------------------
// K2: FUSED Cholesky (NB=32, wave-0 shfl diag + per-thread row-solve,
//     512-thread trailing update) + blocked triangular inversion.
//     One block per task, 512 threads (8 waves). LDS 64 KB reused per phase.
// ---------------------------------------------------------------------------
__global__ __launch_bounds__(512) void k_cholinv(double* __restrict__ G,
                                                 double* __restrict__ LT,
                                                 double* __restrict__ TI,
                                                 float* __restrict__ TIF) {
    __shared__ double S[8192];          // 64 KB
    __shared__ double dinvs[32];
    int b = blockIdx.x, tid = threadIdx.x;
    double* Gb = G + b * 65536;
    double* LTb = LT + b * 65536;
    double* TIb = TI + b * 65536;
    float* TIFb = TIF + b * 65536;

    // ---------------- phase 1: blocked Cholesky, NB=32 ----------------
#define PP(p, row) S[(p) * 256 + (((row) + (p)) & 255)]
    for (int k0 = 0; k0 < 256; k0 += 32) {
        int rows = 256 - k0;
        for (int idx = tid; idx < rows * 32; idx += 512) {
            int r = k0 + (idx >> 5), p = idx & 31;
            PP(p, r) = Gb[r * 256 + k0 + p];
        }
        __syncthreads();
        // wave 0: register Cholesky of the 32x32 diagonal block (lane = row)
        if (tid < 32) {
            double x[32];
#pragma unroll
            for (int p = 0; p < 32; ++p) x[p] = PP(p, k0 + tid);
            for (int p = 0; p < 32; ++p) {
                double dpp = __shfl(x[p], p);
                double d = sqrt(fmax(dpp, 1e-300));
                double inv = 1.0 / d;
                if (tid == p) { x[p] = d; dinvs[p] = inv; }
                else if (tid > p) x[p] *= inv;
                for (int p2 = p + 1; p2 < 32; ++p2) {
                    double lp2 = __shfl(x[p], p2);
                    if (tid >= p2) x[p2] -= x[p] * lp2;
                }
            }
#pragma unroll
            for (int p = 0; p < 32; ++p) PP(p, k0 + tid) = x[p];
        }
        __syncthreads();
        // independent per-thread row-solve for rows >= k0+32
        {
            int i = k0 + 32 + tid;
            if (i < 256) {
                double xr[32];
#pragma unroll
                for (int p = 0; p < 32; ++p) {
                    double v = PP(p, i);
                    for (int p2 = 0; p2 < p; ++p2)
                        v -= xr[p2] * PP(p2, k0 + p);
                    xr[p] = v * dinvs[p];
                }
#pragma unroll
                for (int p = 0; p < 32; ++p) PP(p, i) = xr[p];
            }
        }
        __syncthreads();
        // write finished panel to LT (coalesced along r)
        for (int idx = tid; idx < 8192; idx += 512) {
            int p = idx >> 8, r = idx & 255;
            if (r >= k0 + p) LTb[(k0 + p) * 256 + r] = PP(p, r);
        }
        // trailing SYRK: 32x16 thread grid of 2x2 microtiles, LDS-fed
        int ty = tid >> 4, tx = tid & 15;
        for (int i2 = k0 + 32 + 2 * ty; i2 < 256; i2 += 64) {
            for (int j2 = k0 + 32 + 2 * tx; j2 <= i2 + 1; j2 += 32) {
                double g00 = 0.0, g01 = 0.0, g10 = 0.0, g11 = 0.0;
#pragma unroll 8
                for (int p = 0; p < 32; ++p) {
                    double l0 = PP(p, i2), l1 = PP(p, i2 + 1);
                    double q0 = PP(p, j2), q1 = PP(p, j2 + 1);
                    g00 += l0 * q0; g01 += l0 * q1;
                    g10 += l1 * q0; g11 += l1 * q1;
                }
                if (j2 <= i2)     Gb[i2 * 256 + j2]           -= g00;
                if (j2 + 1 <= i2) Gb[i2 * 256 + j2 + 1]       -= g01;
                Gb[(i2 + 1) * 256 + j2] -= g10;
                if (j2 <= i2)     Gb[(i2 + 1) * 256 + j2 + 1] -= g11;
            }
        }
        __syncthreads();
    }
#undef PP

    // ---------------- phase 2: Tinv = L^{-1} ----------------
    // zero strictly-upper of TI/TIF
    for (int idx = tid; idx < 65536; idx += 512) {
        int i = idx >> 8, k = idx & 255;
        if (k > i) { TIb[idx] = 0.0; TIFb[idx] = 0.0f; }
    }
    // stage 8 diagonal 32x32 blocks: S[g*1024 + k*32 + i] = L[32g+i][32g+k]
    for (int idx = tid; idx < 8192; idx += 512) {
        int g = idx >> 10, rem = idx & 1023, k = rem >> 5, i = rem & 31;
        S[idx] = LTb[(32 * g + k) * 256 + 32 * g + i];
    }
    __syncthreads();
    // invert diagonal blocks (256 threads: 8 blocks x 32 columns)
    if (tid < 256) {
        int g = tid >> 5, j = tid & 31;
        const double* D = S + g * 1024;
        double x[32];
#pragma unroll
        for (int i = 0; i < 32; ++i) {
            double s = (i == j) ? 1.0 : 0.0;
#pragma unroll
            for (int k = 0; k < i; ++k) {
                double lv = D[k * 32 + i];
                s -= (k >= j) ? lv * x[k] : 0.0;
            }
            x[i] = (i >= j) ? s * (1.0 / D[i * 32 + i]) : 0.0;
        }
#pragma unroll
        for (int i = 0; i < 32; ++i) {
            int gi = 32 * g + i, gj = 32 * g + j;
            TIb[gi * 256 + gj] = x[i];
            TIFb[gi * 256 + gj] = (float)x[i];
        }
    }
    __syncthreads();
    // off-diagonal blocks, LDS-staged block GEMMs:
    //   B = sum_K L[I][K] Tinv[K][J];  Tinv[I][J] = -Dinv_I @ B
    double* Lsh = S;            // 32x32
    double* Tsh = S + 1024;
    double* Bsh = S + 2048;
    double* Dsh = S + 3072;
    int e0 = tid, e1 = tid + 512;
    int i0e = e0 >> 5, j0e = e0 & 31;
    int i1e = e1 >> 5, j1e = e1 & 31;
    for (int I = 1; I < 8; ++I) {
        for (int idx = tid; idx < 1024; idx += 512) {
            int ii = idx >> 5, kk = idx & 31;
            Dsh[idx] = TIb[(32 * I + ii) * 256 + 32 * I + kk];   // Dinv_I[ii][kk]
        }
        __syncthreads();
        for (int J = I - 1; J >= 0; --J) {
            double a0 = 0.0, a1 = 0.0;
            for (int K = J; K < I; ++K) {
                __syncthreads();
                for (int idx = tid; idx < 1024; idx += 512) {
                    int kk = idx >> 5, ee = idx & 31;
                    Lsh[idx] = LTb[(32 * K + kk) * 256 + 32 * I + ee];  // L[I*32+ee][K*32+kk]
                    Tsh[idx] = TIb[(32 * K + kk) * 256 + 32 * J + ee];  // Tinv[K*32+kk][J*32+ee]
                }
                __syncthreads();
#pragma unroll 8
                for (int kk = 0; kk < 32; ++kk) {
                    a0 += Lsh[kk * 32 + i0e] * Tsh[kk * 32 + j0e];
                    a1 += Lsh[kk * 32 + i1e] * Tsh[kk * 32 + j1e];
                }
            }
            __syncthreads();
            Bsh[e0] = a0; Bsh[e1] = a1;
            __syncthreads();
            double c0 = 0.0, c1 = 0.0;
#pragma unroll 8
            for (int kk = 0; kk < 32; ++kk) {
                c0 -= Dsh[i0e * 32 + kk] * Bsh[kk * 32 + j0e];
                c1 -= Dsh[i1e * 32 + kk] * Bsh[kk * 32 + j1e];
            }
            TIb[(32 * I + i0e) * 256 + 32 * J + j0e] = c0;
            TIb[(32 * I + i1e) * 256 + 32 * J + j1e] = c1;
            TIFb[(32 * I + i0e) * 256 + 32 * J + j0e] = (float)c0;
            TIFb[(32 * I + i1e) * 256 + 32 * J + j1e] = (float)c1;
            __syncthreads();
        }
    }
}

// ---------------------------------------------------------------------------
// K3: FUSED solve: Z = Tinv @ (RHS + MPN); M = Tinv^T @ Z  -> RHS buffer.
//     One block per task, 512 threads.
// ---------------------------------------------------------------------------
__global__ __launch_bounds__(512) void k_solve(const double* __restrict__ TI,
                                               const double* __restrict__ MPN,
                                               double* __restrict__ RHS,
                                               double* __restrict__ Z) {
    __shared__ double As[2048];     // 16 KB
    __shared__ double Bs[64][64];   // 32 KB
    int b = blockIdx.x, tid = threadIdx.x;
    int c = tid & 63, rg = tid >> 6;              // rg 0..7
    const double* TIb = TI + b * 65536;
    double* Rb = RHS + b * 16384;
    double* Zb = Z + b * 16384;
    // phase A: Z = Tinv @ (RHS + MPN), 32-row strips
    for (int i0 = 0; i0 < 8; ++i0) {
        double acc[4] = {0.0, 0.0, 0.0, 0.0};
        int ktiles = (i0 >> 1) + 1;
        for (int kt = 0; kt < ktiles; ++kt) {
            __syncthreads();
            for (int idx = tid; idx < 2048; idx += 512) {
                int rr = idx >> 6, kk = idx & 63;
                As[rr * 64 + kk] = TIb[(i0 * 32 + rr) * 256 + kt * 64 + kk];
            }
            for (int idx = tid; idx < 4096; idx += 512) {
                int kk = idx >> 6, cc = idx & 63;
                Bs[kk][cc] = Rb[(kt * 64 + kk) * 64 + cc] + MPN[(kt * 64 + kk) * 64 + cc];
            }
            __syncthreads();
            for (int kk = 0; kk < 64; ++kk) {
                double bv = Bs[kk][c];
#pragma unroll
                for (int u = 0; u < 4; ++u)
                    acc[u] += As[(rg * 4 + u) * 64 + kk] * bv;
            }
        }
#pragma unroll
        for (int u = 0; u < 4; ++u)
            Zb[(i0 * 32 + rg * 4 + u) * 64 + c] = acc[u];
    }
    __syncthreads();
    // phase B: M = Tinv^T @ Z  (writes RHS)
    for (int i0 = 0; i0 < 8; ++i0) {
        double acc[4] = {0.0, 0.0, 0.0, 0.0};
        for (int kt = i0 >> 1; kt < 4; ++kt) {
            __syncthreads();
            for (int idx = tid; idx < 2048; idx += 512) {
                int kk = idx >> 5, ri = idx & 31;
                As[kk * 32 + ri] = TIb[(kt * 64 + kk) * 256 + i0 * 32 + ri];
            }
            for (int idx = tid; idx < 4096; idx += 512) {
                int kk = idx >> 6, cc = idx & 63;
                Bs[kk][cc] = Zb[(kt * 64 + kk) * 64 + cc];
            }
            __syncthreads();
            for (int kk = 0; kk < 64; ++kk) {
                double bv = Bs[kk][c];
#pragma unroll
                for (int u = 0; u < 4; ++u)
                    acc[u] += As[kk * 32 + rg * 4 + u] * bv;
            }
        }
#pragma unroll
        for (int u = 0; u < 4; ++u)
            Rb[(i0 * 32 + rg * 4 + u) * 64 + c] = acc[u];
    }
}

// ---------------------------------------------------------------------------
// K4: FUSED predict: spread GEMM (triangular, accW in registers) + mu GEMM +
//     SPREAD write + nll partial -> atomicAdd. Grid (B, 8), 256 threads.
// ---------------------------------------------------------------------------
__global__ __launch_bounds__(256) void k_predict(const float* __restrict__ PHIQ,
                                                 const double* __restrict__ M,
                                                 const float* __restrict__ TIF,
                                                 const float* __restrict__ YQ,
                                                 const float* __restrict__ SE,
                                                 float* __restrict__ SPREAD,
                                                 double* __restrict__ NLLACC,
                                                 float* __restrict__ MU) {
    __shared__ float Qs[64][65];
    __shared__ float Ts[64][65];
    __shared__ float Ms[64][64];
    __shared__ double nred[64];
    int b = blockIdx.x, q0 = blockIdx.y * 64, tid = threadIdx.x;
    int tx = tid & 15, ty = tid >> 4;
    const float* Qb = PHIQ + b * (NQ * DIN) + q0 * DIN;
    const double* Mb = M + b * 16384;
    const float* Tb = TIF + b * 65536;
    float accW[4][4][4];   // [I][r][s]
    float accM[4][4];
#pragma unroll
    for (int I = 0; I < 4; ++I)
#pragma unroll
        for (int r = 0; r < 4; ++r)
#pragma unroll
            for (int s = 0; s < 4; ++s) accW[I][r][s] = 0.0f;
#pragma unroll
    for (int r = 0; r < 4; ++r)
#pragma unroll
        for (int s = 0; s < 4; ++s) accM[r][s] = 0.0f;

    for (int kt = 0; kt < 4; ++kt) {
        int k0 = kt * 64;
        __syncthreads();
        for (int idx = tid; idx < 4096; idx += 256) {
            int r = idx >> 6, cc = idx & 63;
            Qs[r][cc] = Qb[r * 256 + k0 + cc];
            Ms[r][cc] = (float)Mb[(k0 + r) * 64 + cc];
        }
        __syncthreads();
        // mu accumulate
        for (int kk = 0; kk < 64; ++kk) {
            float a0 = Qs[4 * ty + 0][kk], a1 = Qs[4 * ty + 1][kk];
            float a2 = Qs[4 * ty + 2][kk], a3 = Qs[4 * ty + 3][kk];
            float b0 = Ms[kk][4 * tx + 0], b1 = Ms[kk][4 * tx + 1];
            float b2 = Ms[kk][4 * tx + 2], b3 = Ms[kk][4 * tx + 3];
            accM[0][0] += a0 * b0; accM[0][1] += a0 * b1; accM[0][2] += a0 * b2; accM[0][3] += a0 * b3;
            accM[1][0] += a1 * b0; accM[1][1] += a1 * b1; accM[1][2] += a1 * b2; accM[1][3] += a1 * b3;
            accM[2][0] += a2 * b0; accM[2][1] += a2 * b1; accM[2][2] += a2 * b2; accM[2][3] += a2 * b3;
            accM[3][0] += a3 * b0; accM[3][1] += a3 * b1; accM[3][2] += a3 * b2; accM[3][3] += a3 * b3;
        }
        // spread accumulate for I >= kt
#pragma unroll
        for (int I = 0; I < 4; ++I) {
            if (I >= kt) {
                __syncthreads();
                for (int idx = tid; idx < 4096; idx += 256) {
                    int r = idx >> 6, cc = idx & 63;
                    Ts[cc][r] = Tb[(I * 64 + r) * 256 + k0 + cc];
                }
                __syncthreads();
                for (int kk = 0; kk < 64; ++kk) {
                    float a0 = Qs[4 * ty + 0][kk], a1 = Qs[4 * ty + 1][kk];
                    float a2 = Qs[4 * ty + 2][kk], a3 = Qs[4 * ty + 3][kk];
                    float b0 = Ts[kk][4 * tx + 0], b1 = Ts[kk][4 * tx + 1];
                    float b2 = Ts[kk][4 * tx + 2], b3 = Ts[kk][4 * tx + 3];
                    accW[I][0][0] += a0 * b0; accW[I][0][1] += a0 * b1; accW[I][0][2] += a0 * b2; accW[I][0][3] += a0 * b3;
                    accW[I][1][0] += a1 * b0; accW[I][1][1] += a1 * b1; accW[I][1][2] += a1 * b2; accW[I][1][3] += a1 * b3;
                    accW[I][2][0] += a2 * b0; accW[I][2][1] += a2 * b1; accW[I][2][2] += a2 * b2; accW[I][2][3] += a2 * b3;
                    accW[I][3][0] += a3 * b0; accW[I][3][1] += a3 * b1; accW[I][3][2] += a3 * b2; accW[I][3][3] += a3 * b3;
                }
            }
        }
    }
    // epilogue: mu write, spread, nll
    float se = SE[0];
#pragma unroll
    for (int r = 0; r < 4; ++r) {
        int q = q0 + 4 * ty + r;
        float4 v = make_float4(accM[r][0], accM[r][1], accM[r][2], accM[r][3]);
        *(float4*)&MU[((size_t)b * NQ + q) * 64 + 4 * tx] = v;
        float4 y = *(const float4*)&YQ[((size_t)b * NQ + q) * 64 + 4 * tx];
        float dx = y.x - v.x, dy = y.y - v.y, dz = y.z - v.z, dw = y.w - v.w;
        float qs = dx * dx + dy * dy + dz * dz + dw * dw;
        float p = 0.0f;
#pragma unroll
        for (int I = 0; I < 4; ++I)
#pragma unroll
            for (int s = 0; s < 4; ++s) p += accW[I][r][s] * accW[I][r][s];
        qs += __shfl_down(qs, 8, 16);
        qs += __shfl_down(qs, 4, 16);
        qs += __shfl_down(qs, 2, 16);
        qs += __shfl_down(qs, 1, 16);
        p += __shfl_down(p, 8, 16);
        p += __shfl_down(p, 4, 16);
        p += __shfl_down(p, 2, 16);
        p += __shfl_down(p, 1, 16);
        if (tx == 0) {
            float sp = 1.0f + p;
            SPREAD[b * 512 + q] = sp;
            nred[ty * 4 + r] = (double)(64.0f * (logf(sp) + logf(se)) + qs / (sp * se));
        }
    }
    __syncthreads();
    for (int s = 32; s > 0; s >>= 1) {
        if (tid < s) nred[tid] += nred[tid + s];
        __syncthreads();
    }
    if (tid == 0) atomicAdd(NLLACC, nred[0] * (1.0 / 65536.0));
}

// ---------------------------------------------------------------------------
// K5 (runs LAST): stream sig; overwrites scratch in d_out; writes nll scalar.
// ---------------------------------------------------------------------------
__global__ __launch_bounds__(256) void k_sig(const float* __restrict__ SPREAD,
                                             const float* __restrict__ SE,
                                             const double* __restrict__ NLLACC,
                                             float* __restrict__ out) {
    __shared__ float sv_s;
    int bq = blockIdx.x, tid = threadIdx.x;
    if (bq == 0 && tid == 0) out[NLL_IDX] = (float)NLLACC[0];
    if (tid == 0) sv_s = SPREAD[bq] * SE[0];
    __syncthreads();
    float sv = sv_s;
    float* base = out + (size_t)MU_SIZE + (size_t)bq * 4096;
    int i = tid >> 2;
    int jb = (tid & 3) << 4;
    int d = i - jb;
    float vals[16];
#pragma unroll
    for (int t = 0; t < 16; ++t) vals[t] = (t == d) ? sv : 0.0f;
    float4* p = (float4*)(base + tid * 16);
    p[0] = make_float4(vals[0], vals[1], vals[2], vals[3]);
    p[1] = make_float4(vals[4], vals[5], vals[6], vals[7]);
    p[2] = make_float4(vals[8], vals[9], vals[10], vals[11]);
    p[3] = make_float4(vals[12], vals[13], vals[14], vals[15]);
}

// ---------------------------------------------------------------------------
extern "C" void kernel_launch(void* const* d_in, const int* in_sizes, int n_in,
                              void* d_out, int out_size, void* d_ws, size_t ws_size,
                              hipStream_t stream) {
    const float* PHI_S = (const float*)d_in[0];
    const float* Y_S   = (const float*)d_in[1];
    const float* PHI_Q = (const float*)d_in[2];
    const float* Y_Q   = (const float*)d_in[3];
    const float* MP    = (const float*)d_in[4];
    const float* AP    = (const float*)d_in[5];
    const float* SE    = (const float*)d_in[6];
    float* out = (float*)d_out;

    // Big scratch inside sig region of d_out (dead before k_sig runs last).
    double* scratch = (double*)(out + MU_SIZE);
    double* G    = scratch;                    // 8,388,608 dbl
    double* LT   = G + 8388608;                // 8,388,608 dbl
    double* RHS  = LT + 8388608;               // 2,097,152 dbl (-> becomes M)
    double* Z    = RHS + 2097152;              // 2,097,152 dbl
    double* TI   = Z + 2097152;                // 8,388,608 dbl
    double* Spd  = TI + 8388608;               // 65,536 dbl
    double* MPN  = Spd + 65536;                // 16,384 dbl
    float*  TIF  = (float*)(MPN + 16384);      // 8,388,608 f32
    // Small persistent scratch (survives until k_sig) in d_ws.
    float*  SPREAD = (float*)d_ws;                        // 65,536 f32
    double* NLLACC = (double*)((char*)d_ws + 65536 * 4);  // 1 dbl

    k_prior_sp<<<256, 256, 0, stream>>>(AP, Spd, NLLACC);
    k_build   <<<dim3(B_T, 15), 256, 0, stream>>>(PHI_S, Y_S, MP, Spd, G, RHS, MPN);
    k_cholinv <<<B_T, 512, 0, stream>>>(G, LT, TI, TIF);
    k_solve   <<<B_T, 512, 0, stream>>>(TI, MPN, RHS, Z);
    k_predict <<<dim3(B_T, 8), 256, 0, stream>>>(PHI_Q, RHS, TIF, Y_Q, SE,
                                                 SPREAD, NLLACC, out);
    k_sig     <<<65536, 256, 0, stream>>>(SPREAD, SE, NLLACC, out);   // LAST
}

// Round 7
// 2433.194 us; speedup vs baseline: 1.3646x; 1.3646x over previous
//
#include <hip/hip_runtime.h>
#include <math.h>

#define B_T   128
#define NS    128
#define NQ    512
#define DIN   256
#define DOUT  64

#define MU_SIZE  (B_T*NQ*DOUT)            // 4,194,304 floats
#define SIG_SIZE (B_T*NQ*DOUT*DOUT)       // 268,435,456 floats
#define NLL_IDX  (MU_SIZE + SIG_SIZE)     // 272,629,760

// ---------------------------------------------------------------------------
// K0: Sp = A @ A^T  (fp64 accumulate); also zeroes the NLL accumulator.
// ---------------------------------------------------------------------------
__global__ __launch_bounds__(256) void k_prior_sp(const float* __restrict__ A,
                                                  double* __restrict__ Sp,
                                                  double* __restrict__ NLLACC) {
    __shared__ float Ai[16][260];
    __shared__ float Aj[16][260];
    int bi = blockIdx.x;
    int i0 = (bi >> 4) << 4;
    int j0 = (bi & 15) << 4;
    int tid = threadIdx.x;
    if (bi == 0 && tid == 0) NLLACC[0] = 0.0;
    for (int idx = tid; idx < 16 * 256; idx += 256) {
        int r = idx >> 8, c = idx & 255;
        Ai[r][c] = A[(i0 + r) * 256 + c];
        Aj[r][c] = A[(j0 + r) * 256 + c];
    }
    __syncthreads();
    int r = tid >> 4, c = tid & 15;
    double acc = 0.0;
    for (int k = 0; k < 256; ++k)
        acc += (double)Ai[r][k] * (double)Aj[c][k];
    Sp[(i0 + r) * 256 + (j0 + c)] = acc;
}

// ---------------------------------------------------------------------------
// K1: G_b = Phi_s^T Phi_s + Sp   (lower-triangle 64x64 tiles only, fp64)
// ---------------------------------------------------------------------------
__global__ __launch_bounds__(256) void k_build_G(const float* __restrict__ PHI,
                                                 const double* __restrict__ Sp,
                                                 double* __restrict__ G) {
    __shared__ float As[128][64];
    __shared__ float Bs[128][64];
    int b = blockIdx.x;
    int by = blockIdx.y;
    int ti = 0;
    while (((ti + 1) * (ti + 2)) / 2 <= by) ti++;
    int tj = by - (ti * (ti + 1)) / 2;
    int i0 = ti * 64, j0 = tj * 64;
    int tid = threadIdx.x;
    const float* Pb = PHI + b * (NS * DIN);
    for (int idx = tid; idx < 128 * 64; idx += 256) {
        int n = idx >> 6, c = idx & 63;
        As[n][c] = Pb[n * 256 + i0 + c];
        Bs[n][c] = Pb[n * 256 + j0 + c];
    }
    __syncthreads();
    int tx = tid & 15, ty = tid >> 4;
    double acc[4][4];
#pragma unroll
    for (int r = 0; r < 4; ++r)
#pragma unroll
        for (int s = 0; s < 4; ++s) acc[r][s] = 0.0;
    for (int n = 0; n < 128; ++n) {
        float a0 = As[n][4 * ty + 0], a1 = As[n][4 * ty + 1];
        float a2 = As[n][4 * ty + 2], a3 = As[n][4 * ty + 3];
        float b0 = Bs[n][4 * tx + 0], b1 = Bs[n][4 * tx + 1];
        float b2 = Bs[n][4 * tx + 2], b3 = Bs[n][4 * tx + 3];
        acc[0][0] += (double)a0 * b0; acc[0][1] += (double)a0 * b1;
        acc[0][2] += (double)a0 * b2; acc[0][3] += (double)a0 * b3;
        acc[1][0] += (double)a1 * b0; acc[1][1] += (double)a1 * b1;
        acc[1][2] += (double)a1 * b2; acc[1][3] += (double)a1 * b3;
        acc[2][0] += (double)a2 * b0; acc[2][1] += (double)a2 * b1;
        acc[2][2] += (double)a2 * b2; acc[2][3] += (double)a2 * b3;
        acc[3][0] += (double)a3 * b0; acc[3][1] += (double)a3 * b1;
        acc[3][2] += (double)a3 * b2; acc[3][3] += (double)a3 * b3;
    }
    double* Gb = G + b * 65536;
#pragma unroll
    for (int r = 0; r < 4; ++r) {
        int i = i0 + 4 * ty + r;
#pragma unroll
        for (int s = 0; s < 4; ++s) {
            int j = j0 + 4 * tx + s;
            Gb[i * 256 + j] = acc[r][s] + Sp[i * 256 + j];
        }
    }
}

// ---------------------------------------------------------------------------
// K2: by<4: RHS_b = Phi_s^T Y_s (raw, MPN added later in k_gemm_Z);
//     by==4 && b<4: MPN = Sp @ m_prior (64-row slice per block).
// ---------------------------------------------------------------------------
__global__ __launch_bounds__(256) void k_build_rhs(const float* __restrict__ PHI,
                                                   const float* __restrict__ Y,
                                                   const float* __restrict__ MP,
                                                   const double* __restrict__ Sp,
                                                   double* __restrict__ RHS,
                                                   double* __restrict__ MPNo) {
    int b = blockIdx.x, by = blockIdx.y, tid = threadIdx.x;
    if (by == 4) {
        if (b >= 4) return;
        for (int out = tid; out < 4096; out += 256) {
            int r = 64 * b + (out >> 6), cc = out & 63;
            double acc = 0.0;
            for (int t = 0; t < 256; ++t)
                acc += Sp[r * 256 + t] * (double)MP[t * 64 + cc];
            MPNo[r * 64 + cc] = acc;
        }
        return;
    }
    __shared__ float As[128][64];
    __shared__ float Ys[128][64];
    int i0 = by * 64;
    const float* Pb = PHI + b * (NS * DIN);
    const float* Yb = Y + b * (NS * DOUT);
    for (int idx = tid; idx < 128 * 64; idx += 256) {
        int n = idx >> 6, c = idx & 63;
        As[n][c] = Pb[n * 256 + i0 + c];
        Ys[n][c] = Yb[n * 64 + c];
    }
    __syncthreads();
    int tx = tid & 15, ty = tid >> 4;
    double acc[4][4];
#pragma unroll
    for (int r = 0; r < 4; ++r)
#pragma unroll
        for (int s = 0; s < 4; ++s) acc[r][s] = 0.0;
    for (int n = 0; n < 128; ++n) {
        float a0 = As[n][4 * ty + 0], a1 = As[n][4 * ty + 1];
        float a2 = As[n][4 * ty + 2], a3 = As[n][4 * ty + 3];
        float y0 = Ys[n][4 * tx + 0], y1 = Ys[n][4 * tx + 1];
        float y2 = Ys[n][4 * tx + 2], y3 = Ys[n][4 * tx + 3];
        acc[0][0] += (double)a0 * y0; acc[0][1] += (double)a0 * y1;
        acc[0][2] += (double)a0 * y2; acc[0][3] += (double)a0 * y3;
        acc[1][0] += (double)a1 * y0; acc[1][1] += (double)a1 * y1;
        acc[1][2] += (double)a1 * y2; acc[1][3] += (double)a1 * y3;
        acc[2][0] += (double)a2 * y0; acc[2][1] += (double)a2 * y1;
        acc[2][2] += (double)a2 * y2; acc[2][3] += (double)a2 * y3;
        acc[3][0] += (double)a3 * y0; acc[3][1] += (double)a3 * y1;
        acc[3][2] += (double)a3 * y2; acc[3][3] += (double)a3 * y3;
    }
    double* Rb = RHS + b * 16384;
#pragma unroll
    for (int r = 0; r < 4; ++r) {
        int i = i0 + 4 * ty + r;
#pragma unroll
        for (int s = 0; s < 4; ++s)
            Rb[i * 64 + 4 * tx + s] = acc[r][s];
    }
}

// ---------------------------------------------------------------------------
// K3: FUSED per-task Cholesky (NB=32, in-place on G, writes LT[k*256+i]) +
//     blocked triangular inversion Tinv = L^{-1} (TI fp64, TIF fp32).
//     One block per task, 256 threads. R5-proven inner patterns, NB doubled
//     to halve the trailing G RMW HBM traffic (measured bottleneck in R5).
// ---------------------------------------------------------------------------
__global__ __launch_bounds__(256) void k_cholinv(double* __restrict__ G,
                                                 double* __restrict__ LT,
                                                 double* __restrict__ TI,
                                                 float* __restrict__ TIF) {
    __shared__ double S[8256];          // 64.5 KB scratch, reused per phase
    int b = blockIdx.x, tid = threadIdx.x;
    double* Gb = G + b * 65536;
    double* LTb = LT + b * 65536;
    double* TIb = TI + b * 65536;
    float* TIFb = TIF + b * 65536;

    // ---------------- phase 1: blocked Cholesky, NB=32 ----------------
    double* P = S;                       // panel: 32 x 258 doubles
#define PCH(p, r) P[(p) * 258 + (r)]
    for (int k0 = 0; k0 < 256; k0 += 32) {
        int rows = 256 - k0;
        for (int idx = tid; idx < rows * 32; idx += 256) {
            int r = k0 + (idx >> 5), p = idx & 31;
            PCH(p, r) = Gb[r * 256 + k0 + p];
        }
        __syncthreads();
        for (int p = 0; p < 32; ++p) {
            int k = k0 + p;
            if (tid >= k) {
                double v = PCH(p, tid);
                for (int p2 = 0; p2 < p; ++p2) v -= PCH(p2, tid) * PCH(p2, k);
                PCH(p, tid) = v;
            }
            __syncthreads();
            double d = sqrt(fmax(PCH(p, k), 1e-300));
            double inv = 1.0 / d;
            if (tid > k) PCH(p, tid) *= inv;
            else if (tid == k) PCH(p, tid) = d;
            __syncthreads();
        }
        // write finished panel (coalesced along i)
        for (int p = 0; p < 32; ++p) {
            int k = k0 + p;
            if (tid >= k) LTb[k * 256 + tid] = PCH(p, tid);
        }
        // trailing update: 2x2 microtile per thread, 32-deep REGISTER panel
        int ty = tid >> 4, tx = tid & 15;
        for (int i2 = k0 + 32 + 2 * ty; i2 < 256; i2 += 32) {
            double pa[32], pb[32];
#pragma unroll
            for (int p = 0; p < 32; ++p) { pa[p] = PCH(p, i2); pb[p] = PCH(p, i2 + 1); }
            for (int j2 = k0 + 32 + 2 * tx; j2 <= i2 + 1; j2 += 32) {
                double g00 = 0.0, g01 = 0.0, g10 = 0.0, g11 = 0.0;
#pragma unroll
                for (int p = 0; p < 32; ++p) {
                    double q0 = PCH(p, j2), q1 = PCH(p, j2 + 1);
                    g00 += pa[p] * q0; g01 += pa[p] * q1;
                    g10 += pb[p] * q0; g11 += pb[p] * q1;
                }
                if (j2 <= i2)     Gb[i2 * 256 + j2]           -= g00;
                if (j2 + 1 <= i2) Gb[i2 * 256 + j2 + 1]       -= g01;
                Gb[(i2 + 1) * 256 + j2] -= g10;               // j2 <= i2+1 by bound
                if (j2 <= i2)     Gb[(i2 + 1) * 256 + j2 + 1] -= g11;
            }
        }
        __syncthreads();
    }
#undef PCH

    // ---------------- phase 2: trinv (SHD = S), R5-verbatim ----------------
    double* SHD = S;   // 8 diag blocks: SHD[g*1024 + k*32 + i] = L[32g+i][32g+k]
    for (int idx = tid; idx < 65536; idx += 256) {
        int i = idx >> 8, k = idx & 255;
        if (k > i) { TIb[idx] = 0.0; TIFb[idx] = 0.0f; }
    }
    for (int idx = tid; idx < 8192; idx += 256) {
        int g = idx >> 10, rem = idx & 1023, k = rem >> 5, i = rem & 31;
        SHD[idx] = LTb[(32 * g + k) * 256 + 32 * g + i];
    }
    __syncthreads();
    {
        int g = tid >> 5, j = tid & 31;
        const double* D = SHD + g * 1024;       // D[k*32+i] = L[i][k]
        double x[32];
#pragma unroll
        for (int i = 0; i < 32; ++i) {
            double s = (i == j) ? 1.0 : 0.0;
#pragma unroll
            for (int k = 0; k < i; ++k) {
                double lv = D[k * 32 + i];
                s -= (k >= j) ? lv * x[k] : 0.0;
            }
            double inv = 1.0 / D[i * 32 + i];
            x[i] = (i >= j) ? s * inv : 0.0;
        }
#pragma unroll
        for (int i = 0; i < 32; ++i) {
            int gi = 32 * g + i, gj = 32 * g + j;
            TIb[gi * 256 + gj] = x[i];
            TIFb[gi * 256 + gj] = (float)x[i];
        }
    }
    __syncthreads();
    double* Bsh = SHD;
    int j = tid & 31, ig = tid >> 5;
    for (int I = 1; I < 8; ++I) {
        for (int J = I - 1; J >= 0; --J) {
            double acc[4] = {0.0, 0.0, 0.0, 0.0};
            for (int K = J; K < I; ++K) {
                for (int kk = 0; kk < 32; ++kk) {
                    double tv = TIb[(32 * K + kk) * 256 + 32 * J + j];
#pragma unroll
                    for (int r = 0; r < 4; ++r) {
                        double lv = LTb[(32 * K + kk) * 256 + 32 * I + ig * 4 + r];
                        acc[r] += lv * tv;
                    }
                }
            }
            __syncthreads();
#pragma unroll
            for (int r = 0; r < 4; ++r) Bsh[(ig * 4 + r) * 32 + j] = acc[r];
            __syncthreads();
            double c[4] = {0.0, 0.0, 0.0, 0.0};
            for (int k = 0; k < 32; ++k) {
                double bv = Bsh[k * 32 + j];
#pragma unroll
                for (int r = 0; r < 4; ++r) {
                    double dv = TIb[(32 * I + ig * 4 + r) * 256 + 32 * I + k];
                    c[r] -= dv * bv;
                }
            }
#pragma unroll
            for (int r = 0; r < 4; ++r) {
                int gi = 32 * I + ig * 4 + r, gj = 32 * J + j;
                TIb[gi * 256 + gj] = c[r];
                TIFb[gi * 256 + gj] = (float)c[r];
            }
        }
        __syncthreads();
    }
}

// ---------------------------------------------------------------------------
// K4a: Z = Tinv @ (RHS + MPN)  (fp64 tiled GEMM, triangular k-skip)
// ---------------------------------------------------------------------------
__global__ __launch_bounds__(256) void k_gemm_Z(const double* __restrict__ TI,
                                                const double* __restrict__ RHS,
                                                const double* __restrict__ MPN,
                                                double* __restrict__ Z) {
    __shared__ double As[32][64];
    __shared__ double Bs[64][64];
    int b = blockIdx.x, i0 = blockIdx.y * 32;
    int tid = threadIdx.x, c = tid & 63, rg = tid >> 6;
    const double* TIb = TI + b * 65536;
    const double* Rb = RHS + b * 16384;
    double* Zb = Z + b * 16384;
    double acc[8] = {};
    for (int k0 = 0; k0 <= i0; k0 += 64) {
        for (int idx = tid; idx < 2048; idx += 256) {
            int r = idx >> 6, kk = idx & 63;
            As[r][kk] = TIb[(i0 + r) * 256 + k0 + kk];
        }
        for (int idx = tid; idx < 4096; idx += 256) {
            int kk = idx >> 6, cc = idx & 63;
            Bs[kk][cc] = Rb[(k0 + kk) * 64 + cc] + MPN[(k0 + kk) * 64 + cc];
        }
        __syncthreads();
        for (int kk = 0; kk < 64; ++kk) {
            double bv = Bs[kk][c];
#pragma unroll
            for (int r = 0; r < 8; ++r)
                acc[r] += As[rg * 8 + r][kk] * bv;
        }
        __syncthreads();
    }
#pragma unroll
    for (int r = 0; r < 8; ++r)
        Zb[(i0 + rg * 8 + r) * 64 + c] = acc[r];
}

// ---------------------------------------------------------------------------
// K4b: M = Tinv^T @ Z  (fp64 tiled GEMM, triangular k-skip), M -> RHS buffer
// ---------------------------------------------------------------------------
__global__ __launch_bounds__(256) void k_gemm_M(const double* __restrict__ TI,
                                                const double* __restrict__ Z,
                                                double* __restrict__ M) {
    __shared__ double As[64][32];
    __shared__ double Bs[64][64];
    int b = blockIdx.x, i0 = blockIdx.y * 32;
    int tid = threadIdx.x, c = tid & 63, rg = tid >> 6;
    const double* TIb = TI + b * 65536;
    const double* Zb = Z + b * 16384;
    double* Mb = M + b * 16384;
    double acc[8] = {};
    for (int k0 = (i0 >> 6) << 6; k0 < 256; k0 += 64) {
        for (int idx = tid; idx < 2048; idx += 256) {
            int kk = idx >> 5, ri = idx & 31;
            As[kk][ri] = TIb[(k0 + kk) * 256 + i0 + ri];
        }
        for (int idx = tid; idx < 4096; idx += 256) {
            int kk = idx >> 6, cc = idx & 63;
            Bs[kk][cc] = Zb[(k0 + kk) * 64 + cc];
        }
        __syncthreads();
        for (int kk = 0; kk < 64; ++kk) {
            double bv = Bs[kk][c];
#pragma unroll
            for (int r = 0; r < 8; ++r)
                acc[r] += As[kk][rg * 8 + r] * bv;
        }
        __syncthreads();
    }
#pragma unroll
    for (int r = 0; r < 8; ++r)
        Mb[(i0 + rg * 8 + r) * 64 + c] = acc[r];
}

// ---------------------------------------------------------------------------
// K5: W = PhiQ @ TinvF^T, PSUM[b][I][q] = sum_{i in I-tile} W[q][i]^2 (fp32)
// ---------------------------------------------------------------------------
__global__ __launch_bounds__(256) void k_spread_gemm(const float* __restrict__ PHIQ,
                                                     const float* __restrict__ TIF,
                                                     float* __restrict__ PSUM) {
    __shared__ float Qs[64][65];   // [q][k]
    __shared__ float Ts[64][65];   // [k][i]
    int b = blockIdx.x, q0 = blockIdx.y * 64, I = blockIdx.z, i0 = I * 64;
    int tid = threadIdx.x, tx = tid & 15, ty = tid >> 4;
    const float* Qb = PHIQ + b * (NQ * DIN) + q0 * DIN;
    const float* Tb = TIF + b * 65536;
    float acc[4][4];
#pragma unroll
    for (int r = 0; r < 4; ++r)
#pragma unroll
        for (int s = 0; s < 4; ++s) acc[r][s] = 0.0f;
    for (int k0 = 0; k0 <= i0; k0 += 64) {
        for (int idx = tid; idx < 4096; idx += 256) {
            int r = idx >> 6, c = idx & 63;
            Qs[r][c] = Qb[r * 256 + k0 + c];
            Ts[c][r] = Tb[(i0 + r) * 256 + k0 + c];
        }
        __syncthreads();
        for (int kk = 0; kk < 64; ++kk) {
            float a0 = Qs[4 * ty + 0][kk], a1 = Qs[4 * ty + 1][kk];
            float a2 = Qs[4 * ty + 2][kk], a3 = Qs[4 * ty + 3][kk];
            float b0 = Ts[kk][4 * tx + 0], b1 = Ts[kk][4 * tx + 1];
            float b2 = Ts[kk][4 * tx + 2], b3 = Ts[kk][4 * tx + 3];
            acc[0][0] += a0 * b0; acc[0][1] += a0 * b1; acc[0][2] += a0 * b2; acc[0][3] += a0 * b3;
            acc[1][0] += a1 * b0; acc[1][1] += a1 * b1; acc[1][2] += a1 * b2; acc[1][3] += a1 * b3;
            acc[2][0] += a2 * b0; acc[2][1] += a2 * b1; acc[2][2] += a2 * b2; acc[2][3] += a2 * b3;
            acc[3][0] += a3 * b0; acc[3][1] += a3 * b1; acc[3][2] += a3 * b2; acc[3][3] += a3 * b3;
        }
        __syncthreads();
    }
#pragma unroll
    for (int r = 0; r < 4; ++r) {
        float p = acc[r][0] * acc[r][0] + acc[r][1] * acc[r][1]
                + acc[r][2] * acc[r][2] + acc[r][3] * acc[r][3];
        p += __shfl_down(p, 8, 16);
        p += __shfl_down(p, 4, 16);
        p += __shfl_down(p, 2, 16);
        p += __shfl_down(p, 1, 16);
        if (tx == 0) PSUM[(size_t)(b * 4 + I) * 512 + q0 + 4 * ty + r] = p;
    }
}

// ---------------------------------------------------------------------------
// K6: mu = Phi_q @ m (fp32), FUSED epilogue: spread combine -> SPREAD,
//     nll partial -> one fp64 atomicAdd per block.
// ---------------------------------------------------------------------------
__global__ __launch_bounds__(256) void k_mu_nll(const float* __restrict__ PHIQ,
                                                const double* __restrict__ M,
                                                const float* __restrict__ YQ,
                                                const float* __restrict__ PSUM,
                                                const float* __restrict__ SE,
                                                float* __restrict__ SPREAD,
                                                double* __restrict__ NLLACC,
                                                float* __restrict__ MU) {
    __shared__ float Qs[64][65];
    __shared__ float Ms[64][64];
    __shared__ double nred[64];
    int b = blockIdx.x, q0 = blockIdx.y * 64, tid = threadIdx.x;
    int tx = tid & 15, ty = tid >> 4;
    const float* Qb = PHIQ + b * (NQ * DIN) + q0 * DIN;
    const double* Mb = M + b * 16384;
    float acc[4][4];
#pragma unroll
    for (int r = 0; r < 4; ++r)
#pragma unroll
        for (int s = 0; s < 4; ++s) acc[r][s] = 0.0f;
    for (int c0 = 0; c0 < 256; c0 += 64) {
        for (int idx = tid; idx < 4096; idx += 256) {
            int r = idx >> 6, c = idx & 63;
            Qs[r][c] = Qb[r * 256 + c0 + c];
            Ms[r][c] = (float)Mb[(c0 + r) * 64 + c];
        }
        __syncthreads();
        for (int kk = 0; kk < 64; ++kk) {
            float a0 = Qs[4 * ty + 0][kk], a1 = Qs[4 * ty + 1][kk];
            float a2 = Qs[4 * ty + 2][kk], a3 = Qs[4 * ty + 3][kk];
            float b0 = Ms[kk][4 * tx + 0], b1 = Ms[kk][4 * tx + 1];
            float b2 = Ms[kk][4 * tx + 2], b3 = Ms[kk][4 * tx + 3];
            acc[0][0] += a0 * b0; acc[0][1] += a0 * b1; acc[0][2] += a0 * b2; acc[0][3] += a0 * b3;
            acc[1][0] += a1 * b0; acc[1][1] += a1 * b1; acc[1][2] += a1 * b2; acc[1][3] += a1 * b3;
            acc[2][0] += a2 * b0; acc[2][1] += a2 * b1; acc[2][2] += a2 * b2; acc[2][3] += a2 * b3;
            acc[3][0] += a3 * b0; acc[3][1] += a3 * b1; acc[3][2] += a3 * b2; acc[3][3] += a3 * b3;
        }
        __syncthreads();
    }
    float se = SE[0];
#pragma unroll
    for (int r = 0; r < 4; ++r) {
        int q = q0 + 4 * ty + r;
        float4 v = make_float4(acc[r][0], acc[r][1], acc[r][2], acc[r][3]);
        *(float4*)&MU[((size_t)b * NQ + q) * 64 + 4 * tx] = v;
        float4 y = *(const float4*)&YQ[((size_t)b * NQ + q) * 64 + 4 * tx];
        float dx = y.x - v.x, dy = y.y - v.y, dz = y.z - v.z, dw = y.w - v.w;
        float qs = dx * dx + dy * dy + dz * dz + dw * dw;
        qs += __shfl_down(qs, 8, 16);
        qs += __shfl_down(qs, 4, 16);
        qs += __shfl_down(qs, 2, 16);
        qs += __shfl_down(qs, 1, 16);
        if (tx == 0) {
            float sp = 1.0f + PSUM[(size_t)(b * 4 + 0) * 512 + q]
                            + PSUM[(size_t)(b * 4 + 1) * 512 + q]
                            + PSUM[(size_t)(b * 4 + 2) * 512 + q]
                            + PSUM[(size_t)(b * 4 + 3) * 512 + q];
            SPREAD[b * 512 + q] = sp;
            float val = 64.0f * (logf(sp) + logf(se)) + qs / (sp * se);
            nred[ty * 4 + r] = (double)val;
        }
    }
    __syncthreads();
    for (int s = 32; s > 0; s >>= 1) {
        if (tid < s) nred[tid] += nred[tid + s];
        __syncthreads();
    }
    if (tid == 0) atomicAdd(NLLACC, nred[0] * (1.0 / 65536.0));
}

// ---------------------------------------------------------------------------
// K7 (runs LAST): stream sig; overwrites scratch in d_out; writes nll scalar.
// ---------------------------------------------------------------------------
__global__ __launch_bounds__(256) void k_sig(const float* __restrict__ SPREAD,
                                             const float* __restrict__ SE,
                                             const double* __restrict__ NLLACC,
                                             float* __restrict__ out) {
    __shared__ float sv_s;
    int bq = blockIdx.x, tid = threadIdx.x;
    if (bq == 0 && tid == 0) out[NLL_IDX] = (float)NLLACC[0];
    if (tid == 0) sv_s = SPREAD[bq] * SE[0];
    __syncthreads();
    float sv = sv_s;
    float* base = out + (size_t)MU_SIZE + (size_t)bq * 4096;
    int i = tid >> 2;
    int jb = (tid & 3) << 4;
    int d = i - jb;
    float vals[16];
#pragma unroll
    for (int t = 0; t < 16; ++t) vals[t] = (t == d) ? sv : 0.0f;
    float4* p = (float4*)(base + tid * 16);
    p[0] = make_float4(vals[0], vals[1], vals[2], vals[3]);
    p[1] = make_float4(vals[4], vals[5], vals[6], vals[7]);
    p[2] = make_float4(vals[8], vals[9], vals[10], vals[11]);
    p[3] = make_float4(vals[12], vals[13], vals[14], vals[15]);
}

// ---------------------------------------------------------------------------
extern "C" void kernel_launch(void* const* d_in, const int* in_sizes, int n_in,
                              void* d_out, int out_size, void* d_ws, size_t ws_size,
                              hipStream_t stream) {
    const float* PHI_S = (const float*)d_in[0];
    const float* Y_S   = (const float*)d_in[1];
    const float* PHI_Q = (const float*)d_in[2];
    const float* Y_Q   = (const float*)d_in[3];
    const float* MP    = (const float*)d_in[4];
    const float* AP    = (const float*)d_in[5];
    const float* SE    = (const float*)d_in[6];
    float* out = (float*)d_out;

    // Big scratch inside sig region of d_out (dead before k_sig runs last).
    double* scratch = (double*)(out + MU_SIZE);
    double* G    = scratch;                    // 8,388,608 dbl
    double* LT   = G + 8388608;                // 8,388,608 dbl
    double* RHS  = LT + 8388608;               // 2,097,152 dbl (-> becomes M)
    double* Z    = RHS + 2097152;              // 2,097,152 dbl
    double* TI   = Z + 2097152;                // 8,388,608 dbl
    double* Spd  = TI + 8388608;               // 65,536 dbl
    double* MPN  = Spd + 65536;                // 16,384 dbl
    float*  TIF  = (float*)(MPN + 16384);      // 8,388,608 f32
    float*  PSUM = TIF + 8388608;              // 262,144 f32
    // Small persistent scratch (survives until k_sig) in d_ws.
    float*  SPREAD = (float*)d_ws;                        // 65,536 f32
    double* NLLACC = (double*)((char*)d_ws + 65536 * 4);  // 1 dbl

    k_prior_sp   <<<256, 256, 0, stream>>>(AP, Spd, NLLACC);
    k_build_G    <<<dim3(B_T, 10), 256, 0, stream>>>(PHI_S, Spd, G);
    k_build_rhs  <<<dim3(B_T, 5), 256, 0, stream>>>(PHI_S, Y_S, MP, Spd, RHS, MPN);
    k_cholinv    <<<B_T, 256, 0, stream>>>(G, LT, TI, TIF);
    k_gemm_Z     <<<dim3(B_T, 8), 256, 0, stream>>>(TI, RHS, MPN, Z);
    k_gemm_M     <<<dim3(B_T, 8), 256, 0, stream>>>(TI, Z, RHS);
    k_spread_gemm<<<dim3(B_T, 8, 4), 256, 0, stream>>>(PHI_Q, TIF, PSUM);
    k_mu_nll     <<<dim3(B_T, 8), 256, 0, stream>>>(PHI_Q, RHS, Y_Q, PSUM, SE,
                                                    SPREAD, NLLACC, out);
    k_sig        <<<65536, 256, 0, stream>>>(SPREAD, SE, NLLACC, out);   // LAST
}